// Round 8
// baseline (115.686 us; speedup 1.0000x reference)
//
#include <hip/hip_runtime.h>
#include <math.h>

#define TT 64

// wave-local LDS fence: waitcnt lgkmcnt(0) only (vmcnt untouched).
__device__ __forceinline__ void syncwave() {
    __builtin_amdgcn_wave_barrier();
    __builtin_amdgcn_s_waitcnt(0xC07F);   // vmcnt=63(no wait), expcnt=7, lgkmcnt=0
    __builtin_amdgcn_wave_barrier();
}

// ---- DPP add (VALU-pipe cross-lane). old=0, bound_ctrl=false.
template<int CTRL, int RM>
__device__ __forceinline__ float dppadd(float v) {
    return v + __int_as_float(__builtin_amdgcn_update_dpp(
        0, __float_as_int(v), CTRL, RM, 0xF, false));
}
// inclusive scan over 64 lanes (verified R6/R7)
__device__ __forceinline__ float wscan64(float v) {
    v = dppadd<0x111, 0xF>(v);   // row_shr:1
    v = dppadd<0x112, 0xF>(v);   // row_shr:2
    v = dppadd<0x114, 0xF>(v);   // row_shr:4
    v = dppadd<0x118, 0xF>(v);   // row_shr:8
    v = dppadd<0x142, 0xA>(v);   // row_bcast15 -> rows 1,3
    v = dppadd<0x143, 0xC>(v);   // row_bcast31 -> rows 2,3
    return v;
}
// rotation allreduce within each 16-lane row (verified R7)
__device__ __forceinline__ float rowsum16(float v) {
    v = dppadd<0x121, 0xF>(v);   // row_ror:1
    v = dppadd<0x122, 0xF>(v);   // row_ror:2
    v = dppadd<0x124, 0xF>(v);   // row_ror:4
    v = dppadd<0x128, 0xF>(v);   // row_ror:8
    return v;
}

// ---------------------------------------------------------------------------
// chains (Magnus form, single kernel): block = batch; 9 waves:
//   waves 0-7 = 2 sides x 4 row-pair waves (lane = token t),
//   wave 8    = yb Gauss-Jordan ONLY (runs concurrent with the scan phase —
//               R7 post-mortem: GJ on wave 0 serialized ~2us behind barrier A).
//   Z ~ exp(M), M = [[Dp, -2S],[2S^T, 0]], S = sum_t x_t,
//   Dp = 2(G - G^T), G = sum_t x_t p_{t-1}^T (p = excl prefix, bf16 LDS).
// U = exp(M)E via 6 Taylor terms (wave-local). q-side: U <- yb U.
// dist^2 = 16 - 2||U0^T U1||_F^2. 4 block barriers, none divergent.
// ---------------------------------------------------------------------------
__global__ __launch_bounds__(576, 2) void chains(
    const int* __restrict__ s1, const int* __restrict__ s2,
    const float* __restrict__ qemb, const float* __restrict__ aemb,
    const float* __restrict__ qtr, const float* __restrict__ qbias,
    const float* __restrict__ wf, const float* __restrict__ wb,
    float* __restrict__ out) {
    // p storage: bf16 pairs, stride 100 dwords (16B-aligned, bank-optimal)
    __shared__ __align__(16) unsigned Pb[2][TT][100];     // 51200 B
    __shared__ float Ssm[2 * 8 * 28];                     // 1792 B
    __shared__ float Gm[2][8][8];                         // 512 B
    __shared__ float ybs[32 * 36];                        // 4608 B
    __shared__ float Tb[8 * 2 * 36];                      // 2304 B
    __shared__ float Ufin[2 * 8 * 36];                    // 2304 B
    // union: GJ scratch (pre-barrier-A, wave 8) / Gpart (post-barrier-A)
    __shared__ __align__(16) float scr[512];              // 2048 B -> 64768 B

    float* xbp   = scr;          // [192]
    float* Augp  = scr + 192;    // [8*16]
    float* Hmp   = scr + 320;    // [192]
    float* Gpart = scr;          // [2][4][4][16]

    const int tid = threadIdx.x;
    const int w   = tid >> 6;        // wave 0..8
    const int sde = (w >> 2) & 1;    // side 0=q, 1=a (waves 0-7)
    const int v   = w & 3;           // row pair {2v, 2v+1}
    const int t   = tid & 63;        // token / lane
    const int b   = blockIdx.x;

    float x[48];

    if (w < 8) {
        // ---- scan + pack (two passes: rows 2v, 2v+1); no barriers inside
        const int* sent = sde ? s2 : s1;
        const float* emb = sde ? aemb : qemb;
        const int id = sent[b * TT + t];
        const float* xbase  = emb + (size_t)id * 192 + v * 48;
        const float* trbase = qtr + v * 48;

        #pragma unroll
        for (int pass = 0; pass < 2; ++pass) {
            {
                const float4* xp = (const float4*)(xbase + pass * 24);
                float4 xv[6];
                #pragma unroll
                for (int u = 0; u < 6; ++u) xv[u] = xp[u];
                if (sde == 0) {
                    const float4* tp = (const float4*)(trbase + pass * 24);
                    #pragma unroll
                    for (int u = 0; u < 6; ++u) {
                        const float4 tv = tp[u];
                        xv[u].x *= tv.x; xv[u].y *= tv.y;
                        xv[u].z *= tv.z; xv[u].w *= tv.w;
                    }
                }
                #pragma unroll
                for (int u = 0; u < 6; ++u) {
                    x[pass * 24 + 4 * u + 0] = xv[u].x;
                    x[pass * 24 + 4 * u + 1] = xv[u].y;
                    x[pass * 24 + 4 * u + 2] = xv[u].z;
                    x[pass * 24 + 4 * u + 3] = xv[u].w;
                }
            }
            float inc[24];
            #pragma unroll
            for (int k = 0; k < 24; ++k) inc[k] = wscan64(x[pass * 24 + k]);

            const int a = 2 * v + pass;
            if (t == 63) {   // S totals
                float4* sp = (float4*)&Ssm[(sde * 8 + a) * 28];
                sp[0] = make_float4(inc[0], inc[1], inc[2], inc[3]);
                sp[1] = make_float4(inc[4], inc[5], inc[6], inc[7]);
                sp[2] = make_float4(inc[8], inc[9], inc[10], inc[11]);
                sp[3] = make_float4(inc[12], inc[13], inc[14], inc[15]);
                sp[4] = make_float4(inc[16], inc[17], inc[18], inc[19]);
                sp[5] = make_float4(inc[20], inc[21], inc[22], inc[23]);
            }
            unsigned pk[12];
            #pragma unroll
            for (int k = 0; k < 24; k += 2) {
                const float e0 = inc[k] - x[pass * 24 + k];
                const float e1 = inc[k + 1] - x[pass * 24 + k + 1];
                pk[k >> 1] = (__float_as_uint(e0) >> 16) |
                             (__float_as_uint(e1) & 0xFFFF0000u);
            }
            uint4* dst = (uint4*)&Pb[sde][t][a * 12];
            dst[0] = make_uint4(pk[0], pk[1], pk[2], pk[3]);
            dst[1] = make_uint4(pk[4], pk[5], pk[6], pk[7]);
            dst[2] = make_uint4(pk[8], pk[9], pk[10], pk[11]);
        }
    } else {
        // ---- wave 8: yb = cayley(bias), exact Gauss-Jordan (wave-sync only,
        // R3-verified pattern). Runs concurrent with waves 0-7's scan.
        xbp[t] = qbias[t]; xbp[t + 64] = qbias[t + 64]; xbp[t + 128] = qbias[t + 128];
        syncwave();
        const int gi = t >> 3, gj = t & 7;
        float a = (gi == gj) ? 1.0f : 0.0f;
        for (int k = 0; k < 24; ++k) a += xbp[gi * 24 + k] * xbp[gj * 24 + k];
        Augp[gi * 16 + gj] = a;
        Augp[gi * 16 + gj + 8] = (gi == gj) ? 1.0f : 0.0f;
        syncwave();
        for (int k = 0; k < 8; ++k) {
            const float piv = Augp[k * 16 + k];
            syncwave();
            if (gi == k) {
                const float ip = 1.0f / piv;
                Augp[k * 16 + gj] *= ip;
                Augp[k * 16 + gj + 8] *= ip;
            }
            syncwave();
            const float f = Augp[gi * 16 + k];
            syncwave();
            if (gi != k) {
                Augp[gi * 16 + gj]     -= f * Augp[k * 16 + gj];
                Augp[gi * 16 + gj + 8] -= f * Augp[k * 16 + gj + 8];
            }
            syncwave();
        }
        for (int idx = t; idx < 192; idx += 64) {
            const int r = idx / 24, c = idx % 24;
            float h = 0.0f;
            for (int m = 0; m < 8; ++m) h += Augp[r * 16 + 8 + m] * xbp[m * 24 + c];
            Hmp[idx] = h;
        }
        syncwave();
        for (int idx = t; idx < 1024; idx += 64) {
            const int r = idx >> 5, c = idx & 31;
            float vv;
            if (r < 8 && c < 8) {
                vv = 2.0f * Augp[r * 16 + 8 + c] - ((r == c) ? 1.0f : 0.0f);
            } else if (r < 8) {
                vv = -2.0f * Hmp[r * 24 + (c - 8)];
            } else if (c < 8) {
                vv = 2.0f * Hmp[c * 24 + (r - 8)];
            } else {
                float s2v = 0.0f;
                for (int m = 0; m < 8; ++m)
                    s2v += xbp[m * 24 + (r - 8)] * Hmp[m * 24 + (c - 8)];
                vv = ((r == c) ? 1.0f : 0.0f) - 2.0f * s2v;
            }
            ybs[r * 36 + c] = vv;
        }
        syncwave();
    }
    __syncthreads();   // A: Pb, Ssm, ybs ready; GJ scratch dead

    // ---- G MACs (waves 0-7): rows {2v,2v+1} x 8 p-rows, inner dim 24
    if (w < 8) {
        float Ga[8], Gb[8];
        #pragma unroll
        for (int m = 0; m < 8; ++m) { Ga[m] = 0.0f; Gb[m] = 0.0f; }
        #pragma unroll
        for (int b8 = 0; b8 < 8; ++b8) {
            const uint4* pv = (const uint4*)&Pb[sde][t][b8 * 12];
            const uint4 qa = pv[0], qb = pv[1], qc = pv[2];
            const unsigned ww[12] = {qa.x, qa.y, qa.z, qa.w,
                                     qb.x, qb.y, qb.z, qb.w,
                                     qc.x, qc.y, qc.z, qc.w};
            #pragma unroll
            for (int d = 0; d < 12; ++d) {
                const float p0 = __uint_as_float(ww[d] << 16);
                const float p1 = __uint_as_float(ww[d] & 0xFFFF0000u);
                Ga[b8] = fmaf(x[2 * d],          p0, Ga[b8]);
                Ga[b8] = fmaf(x[2 * d + 1],      p1, Ga[b8]);
                Gb[b8] = fmaf(x[24 + 2 * d],     p0, Gb[b8]);
                Gb[b8] = fmaf(x[24 + 2 * d + 1], p1, Gb[b8]);
            }
        }
        #pragma unroll
        for (int m = 0; m < 8; ++m) { Ga[m] = rowsum16(Ga[m]); Gb[m] = rowsum16(Gb[m]); }
        if ((t & 15) == 0) {
            const int g = t >> 4;
            float4* gp = (float4*)&Gpart[((sde * 4 + v) * 4 + g) * 16];
            gp[0] = make_float4(Ga[0], Ga[1], Ga[2], Ga[3]);
            gp[1] = make_float4(Ga[4], Ga[5], Ga[6], Ga[7]);
            gp[2] = make_float4(Gb[0], Gb[1], Gb[2], Gb[3]);
            gp[3] = make_float4(Gb[4], Gb[5], Gb[6], Gb[7]);
        }
    }
    __syncthreads();   // B

    if (tid < 128) {   // assemble G: entry (side, a, bb)
        const int side = tid >> 6, rem = tid & 63;
        const int a = rem >> 3, bb = rem & 7;
        const int vv = a >> 1, m = (a & 1) * 8 + bb;
        const int base = (side * 4 + vv) * 4 * 16 + m;
        const float g = Gpart[base] + Gpart[base + 16] +
                        Gpart[base + 32] + Gpart[base + 48];
        Gm[side][a][bb] = g;
    }
    __syncthreads();   // C

    // ---- epilogue (waves 0-7): U = exp(M)E, column in 32 lanes, wave-local
    if (w < 8) {
        const int cc = t >> 5;
        const int r  = t & 31;
        const int c  = 2 * (w & 3) + cc;
        float mrow[32];
        if (r < 8) {
            #pragma unroll
            for (int m = 0; m < 8; ++m) mrow[m] = 2.0f * (Gm[sde][r][m] - Gm[sde][m][r]);
            const float4* sp = (const float4*)&Ssm[(sde * 8 + r) * 28];
            #pragma unroll
            for (int u6 = 0; u6 < 6; ++u6) {
                const float4 q = sp[u6];
                mrow[8 + 4 * u6 + 0] = -2.0f * q.x;
                mrow[8 + 4 * u6 + 1] = -2.0f * q.y;
                mrow[8 + 4 * u6 + 2] = -2.0f * q.z;
                mrow[8 + 4 * u6 + 3] = -2.0f * q.w;
            }
        } else {
            #pragma unroll
            for (int m = 0; m < 8; ++m) mrow[m] = 2.0f * Ssm[(sde * 8 + m) * 28 + (r - 8)];
            #pragma unroll
            for (int k = 8; k < 32; ++k) mrow[k] = 0.0f;
        }

        float uacc = (r == c) ? 1.0f : 0.0f;
        float term = uacc;
        const float invn[6] = {1.0f, 0.5f, 1.0f / 3.0f, 0.25f, 0.2f, 1.0f / 6.0f};
        float* tb = &Tb[((w & 7) * 2 + cc) * 36];
        #pragma unroll
        for (int n = 0; n < 6; ++n) {
            tb[r] = term;
            syncwave();
            const float4* tv = (const float4*)tb;
            float dot = 0.0f;
            #pragma unroll
            for (int u8 = 0; u8 < 8; ++u8) {
                const float4 q = tv[u8];
                dot = fmaf(mrow[4 * u8 + 0], q.x, dot);
                dot = fmaf(mrow[4 * u8 + 1], q.y, dot);
                dot = fmaf(mrow[4 * u8 + 2], q.z, dot);
                dot = fmaf(mrow[4 * u8 + 3], q.w, dot);
            }
            term = dot * invn[n];
            uacc += term;
            syncwave();   // WAR before next write
        }
        if (sde == 0) {   // q-side: U <- yb U
            tb[r] = uacc;
            syncwave();
            const float4* tv = (const float4*)tb;
            const float4* yr = (const float4*)&ybs[r * 36];
            float dot = 0.0f;
            #pragma unroll
            for (int u8 = 0; u8 < 8; ++u8) {
                const float4 q = tv[u8], y = yr[u8];
                dot = fmaf(y.x, q.x, dot); dot = fmaf(y.y, q.y, dot);
                dot = fmaf(y.z, q.z, dot); dot = fmaf(y.w, q.w, dot);
            }
            uacc = dot;
        }
        Ufin[(sde * 8 + c) * 36 + r] = uacc;
    }
    __syncthreads();   // D

    // ---- join on wave 0: dist^2 = 16 - 2 ||U0^T U1||_F^2
    if (w == 0) {
        const int a = t >> 3, b2 = t & 7;
        const float4* pa = (const float4*)&Ufin[a * 36];
        const float4* pb = (const float4*)&Ufin[(8 + b2) * 36];
        float dot = 0.0f;
        #pragma unroll
        for (int u8 = 0; u8 < 8; ++u8) {
            const float4 A4 = pa[u8], B4 = pb[u8];
            dot = fmaf(A4.x, B4.x, dot); dot = fmaf(A4.y, B4.y, dot);
            dot = fmaf(A4.z, B4.z, dot); dot = fmaf(A4.w, B4.w, dot);
        }
        float val = dot * dot;
        #pragma unroll
        for (int d = 1; d < 64; d <<= 1) val += __shfl_xor(val, d);
        if (t == 0) {
            const float d2 = 16.0f - 2.0f * val;
            out[b] = -wf[0] * sqrtf(fmaxf(d2, 0.0f)) + wb[0];
        }
    }
}

extern "C" void kernel_launch(void* const* d_in, const int* in_sizes, int n_in,
                              void* d_out, int out_size, void* d_ws, size_t ws_size,
                              hipStream_t stream) {
    const int* s1 = (const int*)d_in[0];
    const int* s2 = (const int*)d_in[1];
    const float* qemb  = (const float*)d_in[2];
    const float* aemb  = (const float*)d_in[3];
    const float* qtr   = (const float*)d_in[4];
    const float* qbias = (const float*)d_in[5];
    const float* wf    = (const float*)d_in[6];
    const float* wb    = (const float*)d_in[7];
    float* out = (float*)d_out;
    (void)d_ws; (void)ws_size; (void)in_sizes; (void)n_in; (void)out_size;

    chains<<<512, 576, 0, stream>>>(s1, s2, qemb, aemb, qtr, qbias, wf, wb, out);
}